// Round 3
// baseline (150.192 us; speedup 1.0000x reference)
//
#include <hip/hip_runtime.h>
#include <hip/hip_bf16.h>

// DiffusionGraphConv on MI355X (gfx950), bf16 MFMA pipeline, round 3.
//
// Pipeline:
//   psq (128^2 2-phase GEMM): Pstack = [A1; 2A1^2-I; A2; 2A2^2-I]
//   big (NEW 256^2 8-phase GEMM): Y[(m',n)][(b,f)] = Pstack @ X0   (M=4096,N=8192,K=1024)
//   final (128^2 2-phase GEMM): out = [X0|Y] @ W2 + bias
//
// ws layout (bf16 elems):
//   PSTK  4M, SUPT 2M, X0T 8M, X0NF 8M, XNF 32M, W2T 80K  (as round 2)

typedef short bf16x8  __attribute__((ext_vector_type(8)));
typedef short short4v __attribute__((ext_vector_type(4)));
typedef float f32x4   __attribute__((ext_vector_type(4)));

constexpr size_t MB1    = 1024ull * 1024ull;
constexpr size_t SZ_MAT = 8192ull * 1024ull;
constexpr size_t OFF_PSTK = 0;
constexpr size_t OFF_SUPT = 4 * MB1;
constexpr size_t OFF_X0T  = 6 * MB1;
constexpr size_t OFF_X0NF = OFF_X0T  + SZ_MAT;
constexpr size_t OFF_XNF  = OFF_X0NF + SZ_MAT;
constexpr size_t OFF_W2T  = OFF_XNF  + 4 * SZ_MAT;

__device__ __forceinline__ unsigned short f2bf(float x) {
  union { float f; unsigned int u; } v; v.f = x;
  unsigned int r = v.u + 0x7fffu + ((v.u >> 16) & 1u);   // RNE
  return (unsigned short)(r >> 16);
}

#define GLD16(gp, lp)                                                         \
  __builtin_amdgcn_global_load_lds(                                           \
      (const __attribute__((address_space(1))) unsigned int*)(gp),            \
      (__attribute__((address_space(3))) unsigned int*)(lp), 16, 0, 0)

__device__ __forceinline__ bf16x8 dsr128(unsigned byteaddr) {
  bf16x8 r;
  asm volatile("ds_read_b128 %0, %1" : "=v"(r) : "v"(byteaddr));
  return r;
}

// ---------------- prep kernels (unchanged from round 2) ----------------

__global__ void cvt_sup_kernel(const float* __restrict__ sup,
                               unsigned short* __restrict__ ws) {
  size_t t = (size_t)blockIdx.x * 256 + threadIdx.x;
  const float4* src = (const float4*)sup;
  float4 v = src[t];
  size_t e = t * 4;
  size_t s = e >> 20;
  size_t r = e & (MB1 - 1);
  short4v o; o[0] = (short)f2bf(v.x); o[1] = (short)f2bf(v.y);
  o[2] = (short)f2bf(v.z); o[3] = (short)f2bf(v.w);
  *(short4v*)&ws[OFF_PSTK + 2 * s * MB1 + r] = o;
}

__global__ void sup_t_kernel(unsigned short* __restrict__ ws) {
  int nt = blockIdx.x, mt = blockIdx.y, s = blockIdx.z;
  const unsigned short* A = ws + OFF_PSTK + (size_t)(2 * s) * MB1;
  unsigned short* AT = ws + OFF_SUPT + (size_t)s * MB1;
  __shared__ unsigned short tile[64][65];
  int t = threadIdx.x; int cl = t & 63; int rg = t >> 6;
#pragma unroll 4
  for (int rr = 0; rr < 16; ++rr) {
    int rl = rr * 4 + rg;
    tile[rl][cl] = A[(size_t)(nt * 64 + rl) * 1024 + mt * 64 + cl];
  }
  __syncthreads();
#pragma unroll 4
  for (int rr = 0; rr < 16; ++rr) {
    int ml = rr * 4 + rg;
    AT[(size_t)(mt * 64 + ml) * 1024 + nt * 64 + cl] = tile[cl][ml];
  }
}

__global__ void w2t_kernel(const float* __restrict__ weight,
                           unsigned short* __restrict__ ws) {
  int t = blockIdx.x * 256 + threadIdx.x;
  int o = t / 640, k = t % 640;
  int m = k >> 7, f = k & 127;
  ws[OFF_W2T + t] = f2bf(weight[(f * 5 + m) * 128 + o]);
}

__global__ void pack_kernel(const float* __restrict__ inputs,
                            const float* __restrict__ state,
                            unsigned short* __restrict__ ws) {
  int b = blockIdx.x, nt = blockIdx.y, ft = blockIdx.z;
  const float* src = ft ? state : inputs;
  unsigned short* x0t  = ws + OFF_X0T;
  unsigned short* x0nf = ws + OFF_X0NF;
  __shared__ unsigned short tile[64][65];
  int tl = threadIdx.x; int fl = tl & 63; int nr = tl >> 6;
#pragma unroll 4
  for (int rr = 0; rr < 16; ++rr) {
    int n_loc = rr * 4 + nr;
    float v = src[(size_t)b * 65536 + (size_t)(nt * 64 + n_loc) * 64 + fl];
    unsigned short bv = f2bf(v);
    tile[n_loc][fl] = bv;
    x0nf[(size_t)(nt * 64 + n_loc) * 8192 + b * 128 + ft * 64 + fl] = bv;
  }
  __syncthreads();
#pragma unroll 4
  for (int rr = 0; rr < 16; ++rr) {
    int f_loc = rr * 4 + nr;
    x0t[(size_t)(b * 128 + ft * 64 + f_loc) * 1024 + nt * 64 + fl] = tile[fl][f_loc];
  }
}

// ---------------- 256^2 8-phase GEMM (big: Y = Pstack @ X0^T-layout) ------
// BM=BN=256, BK=64, 512 thr (8 waves 2x4), wave tile 128x64 (8x4 frags).
// LDS 128KB: buf{0,1} x { A 256x64 | B 256x64 }, 16B-granule XOR swizzle.
// Phase = {ds-read quad (+B at q0), stage 1 half-tile, bar, lgkm0, 16 MFMA,
// [vmcnt(4) at q3], bar}.  Staging schedule (phase idx in iteration of 2
// K-tiles kt=2it,2it+1):  ph0:A0(2it+1) ph1:A1(2it+1) ph2:B0(2it+2)
// ph3:B1(2it+2)+vm4  ph4:A0(2it+2) ph5:A1(2it+2) ph6:B0(2it+3)
// ph7:B1(2it+3)+vm4.  Every staged region's last reader was >=1 phase ago
// (end-of-phase barrier + lgkmcnt(0)-before-MFMA makes that race-free).

#define PHASE(Q, BUF, STAGES, VM4)                                            \
  {                                                                           \
    if ((Q) == 0) {                                                           \
      _Pragma("unroll")                                                       \
      for (int j = 0; j < 4; ++j) {                                           \
        bfr[j][0] = dsr128(bbase + (BUF)*65536u + j*2048u + gk0);             \
        bfr[j][1] = dsr128(bbase + (BUF)*65536u + j*2048u + gk1);             \
      }                                                                       \
    }                                                                         \
    bf16x8 af0k0 = dsr128(abase + (BUF)*65536u + ((Q)*2+0)*2048u + gk0);      \
    bf16x8 af0k1 = dsr128(abase + (BUF)*65536u + ((Q)*2+0)*2048u + gk1);      \
    bf16x8 af1k0 = dsr128(abase + (BUF)*65536u + ((Q)*2+1)*2048u + gk0);      \
    bf16x8 af1k1 = dsr128(abase + (BUF)*65536u + ((Q)*2+1)*2048u + gk1);      \
    STAGES;                                                                   \
    __builtin_amdgcn_sched_barrier(0);                                        \
    __builtin_amdgcn_s_barrier();                                             \
    asm volatile("s_waitcnt lgkmcnt(0)" ::: "memory");                        \
    __builtin_amdgcn_sched_barrier(0);                                        \
    __builtin_amdgcn_s_setprio(1);                                            \
    _Pragma("unroll")                                                         \
    for (int j = 0; j < 4; ++j) {                                             \
      acc[(Q)*2+0][j] = __builtin_amdgcn_mfma_f32_16x16x32_bf16(              \
          af0k0, bfr[j][0], acc[(Q)*2+0][j], 0, 0, 0);                        \
      acc[(Q)*2+1][j] = __builtin_amdgcn_mfma_f32_16x16x32_bf16(              \
          af1k0, bfr[j][0], acc[(Q)*2+1][j], 0, 0, 0);                        \
    }                                                                         \
    _Pragma("unroll")                                                         \
    for (int j = 0; j < 4; ++j) {                                             \
      acc[(Q)*2+0][j] = __builtin_amdgcn_mfma_f32_16x16x32_bf16(              \
          af0k1, bfr[j][1], acc[(Q)*2+0][j], 0, 0, 0);                        \
      acc[(Q)*2+1][j] = __builtin_amdgcn_mfma_f32_16x16x32_bf16(              \
          af1k1, bfr[j][1], acc[(Q)*2+1][j], 0, 0, 0);                        \
    }                                                                         \
    __builtin_amdgcn_s_setprio(0);                                            \
    __builtin_amdgcn_sched_barrier(0);                                        \
    if (VM4) { asm volatile("s_waitcnt vmcnt(4)" ::: "memory"); }             \
    __builtin_amdgcn_s_barrier();                                             \
    __builtin_amdgcn_sched_barrier(0);                                        \
  }

__global__ __launch_bounds__(512, 2)
void gemm8_kernel(unsigned short* __restrict__ ws) {
  extern __shared__ unsigned short lds[];   // 131072 B via launch config

  const unsigned short* Aop = ws + OFF_PSTK;   // [4096][1024]
  const unsigned short* Bop = ws + OFF_X0T;    // [8192][1024] (B^T layout)
  unsigned short* Y = ws + OFF_XNF;            // [4096][8192]

  const int tid = threadIdx.x;
  const int l  = tid & 63, w = tid >> 6;
  const int wr = w >> 2, wc = w & 3;
  const int lm = l & 15, kq = l >> 4;

  // grid 512 = 16 bm x 32 bn; 8x8 tile rectangle per XCD.
  int bid = blockIdx.x;
  int xcd = bid & 7, idx = bid >> 3;
  int bm = ((xcd & 1) << 3) | (idx & 7);
  int bn = ((xcd >> 1) << 3) | (idx >> 3);

  const size_t a_row0 = (size_t)bm * 256;
  const size_t b_row0 = (size_t)bn * 256;

  // staging constants: half-tile = 128 rows x 64k; chunk (c*8+w) = 8 rows.
  const int rl = l >> 3;                 // 0..7 == rowloc&7
  const int kg = (l & 7) ^ rl;           // pre-swizzled source granule

  // ds-read constants
  const unsigned LB =
      (unsigned)(unsigned long long)(__attribute__((address_space(3)))
                                         const unsigned short*)lds;
  const unsigned gk0 = 16u * (unsigned)(kq ^ (lm & 7));
  const unsigned gk1 = gk0 ^ 64u;                       // ^= (1<<2 granule)*16
  const unsigned abase = LB + (unsigned)((wr * 128 + lm) * 128);
  const unsigned bbase = LB + 32768u + (unsigned)((wc * 64 + lm) * 128);

  auto stageA = [&](int buf, int h, int kt) {
#pragma unroll
    for (int c = 0; c < 2; ++c) {
      int rloc = (c * 8 + w) * 8 + rl;
      const unsigned short* gp =
          Aop + ((a_row0 + h * 128 + rloc) << 10) + kt * 64 + kg * 8;
      GLD16(gp, &lds[buf * 32768 + h * 8192 + (c * 8 + w) * 512]);
    }
  };
  auto stageB = [&](int buf, int h, int kt) {
#pragma unroll
    for (int c = 0; c < 2; ++c) {
      int rloc = (c * 8 + w) * 8 + rl;
      const unsigned short* gp =
          Bop + ((b_row0 + h * 128 + rloc) << 10) + kt * 64 + kg * 8;
      GLD16(gp, &lds[buf * 32768 + 16384 + h * 8192 + (c * 8 + w) * 512]);
    }
  };

  f32x4 acc[8][4] = {};
  bf16x8 bfr[4][2];

  // prologue: A(0), B(0) -> buf0; B(1) -> buf1 (A(1) staged in it0 ph0/ph1)
  stageA(0, 0, 0); stageA(0, 1, 0);
  stageB(0, 0, 0); stageB(0, 1, 0);
  stageB(1, 0, 1); stageB(1, 1, 1);
  asm volatile("s_waitcnt vmcnt(4)" ::: "memory");
  __builtin_amdgcn_s_barrier();
  __builtin_amdgcn_sched_barrier(0);

  for (int it = 0; it < 8; ++it) {
    int ka1 = 2 * it + 1;                      // <= 15, never clamps
    int kb2 = 2 * it + 2; if (kb2 > 15) kb2 = 15;   // clamped prefetch (last
    int kb3 = 2 * it + 3; if (kb3 > 15) kb3 = 15;   // iter stages dead data)
    PHASE(0, 0, stageA(1, 0, ka1), 0)
    PHASE(1, 0, stageA(1, 1, ka1), 0)
    PHASE(2, 0, stageB(0, 0, kb2), 0)
    PHASE(3, 0, stageB(0, 1, kb2), 1)
    PHASE(0, 1, stageA(0, 0, kb2), 0)
    PHASE(1, 1, stageA(0, 1, kb2), 0)
    PHASE(2, 1, stageB(1, 0, kb3), 0)
    PHASE(3, 1, stageB(1, 1, kb3), 1)
  }

  // epilogue: Y[(row)][(col)] bf16
#pragma unroll
  for (int i = 0; i < 8; ++i) {
    int rg0 = bm * 256 + wr * 128 + i * 16 + kq * 4;
#pragma unroll
    for (int j = 0; j < 4; ++j) {
      int cg = bn * 256 + wc * 64 + j * 16 + lm;
#pragma unroll
      for (int r = 0; r < 4; ++r)
        Y[(size_t)(rg0 + r) * 8192 + cg] = f2bf(acc[i][j][r]);
    }
  }
}

// ---------------- 128^2 2-phase GEMM (psq + final, unchanged) -------------

template <int MODE, int NJ>
__global__ __launch_bounds__(256)
void gemm_kernel(unsigned short* __restrict__ ws,
                 const float* __restrict__ bias,
                 float* __restrict__ dout) {
  __shared__ short At[128 * 64];
  __shared__ short Bt[32 * NJ * 64];

  const int tid = threadIdx.x;
  const int l   = tid & 63;
  const int w   = tid >> 6;
  const int wr  = w >> 1, wc = w & 1;

  int bm, bn, s = 0;
  const unsigned short* A = nullptr;
  const unsigned short* B;
  int KT;
  if constexpr (MODE == 0) {
    bm = blockIdx.x; bn = blockIdx.y; s = blockIdx.z;
    A = ws + OFF_PSTK + (size_t)(2 * s) * MB1;
    B = ws + OFF_SUPT + (size_t)s * MB1;
    KT = 16;
  } else {
    bm = blockIdx.x; bn = 0;
    B = ws + OFF_W2T;
    KT = 10;
  }

  const int subrow = l >> 3;
  const int koff   = (((l & 7) << 3) ^ (subrow << 3));

  f32x4 acc[4][NJ] = {};

  for (int kt = 0; kt < KT; ++kt) {
#pragma unroll
    for (int c = 0; c < 4; ++c) {
      int chunk = w * 4 + c;
      int rowl  = chunk * 8 + subrow;
      const unsigned short* gp;
      if constexpr (MODE == 2) {
        int rg = bm * 128 + rowl;
        const unsigned short* base =
            (kt < 2) ? (ws + OFF_X0NF)
                     : (ws + OFF_XNF + (size_t)((kt >> 1) - 1) * SZ_MAT);
        gp = base + (size_t)(rg >> 6) * 8192 + (size_t)(rg & 63) * 128 +
             (kt & 1) * 64 + koff;
      } else {
        gp = A + (size_t)(bm * 128 + rowl) * 1024 + kt * 64 + koff;
      }
      GLD16(gp, &At[chunk * 512]);
    }
#pragma unroll
    for (int c = 0; c < NJ; ++c) {
      int chunk = w * NJ + c;
      int rowl  = chunk * 8 + subrow;
      const unsigned short* gp;
      if constexpr (MODE == 2) {
        gp = B + (size_t)rowl * 640 + kt * 64 + koff;
      } else {
        gp = B + (size_t)(bn * (32 * NJ) + rowl) * 1024 + kt * 64 + koff;
      }
      GLD16(gp, &Bt[chunk * 512]);
    }
    __syncthreads();

#pragma unroll
    for (int kk = 0; kk < 2; ++kk) {
      bf16x8 af[4], bfv[NJ];
#pragma unroll
      for (int i = 0; i < 4; ++i) {
        int row = wr * 64 + i * 16 + (l & 15);
        int off = row * 64 + ((kk * 32 + ((l >> 4) << 3)) ^ ((row & 7) << 3));
        af[i] = *(const bf16x8*)&At[off];
      }
#pragma unroll
      for (int j = 0; j < NJ; ++j) {
        int row = wc * (16 * NJ) + j * 16 + (l & 15);
        int off = row * 64 + ((kk * 32 + ((l >> 4) << 3)) ^ ((row & 7) << 3));
        bfv[j] = *(const bf16x8*)&Bt[off];
      }
#pragma unroll
      for (int i = 0; i < 4; ++i)
#pragma unroll
        for (int j = 0; j < NJ; ++j)
          acc[i][j] = __builtin_amdgcn_mfma_f32_16x16x32_bf16(af[i], bfv[j],
                                                              acc[i][j], 0, 0, 0);
    }
    __syncthreads();
  }

  if constexpr (MODE == 0) {
    unsigned short* P = ws + OFF_PSTK + (size_t)(2 * s + 1) * MB1;
#pragma unroll
    for (int i = 0; i < 4; ++i) {
      int rg0 = bm * 128 + wr * 64 + i * 16 + ((l >> 4) << 2);
#pragma unroll
      for (int j = 0; j < NJ; ++j) {
        int cg = bn * (32 * NJ) + wc * (16 * NJ) + j * 16 + (l & 15);
#pragma unroll
        for (int r = 0; r < 4; ++r) {
          int rg = rg0 + r;
          float v = 2.0f * acc[i][j][r] - (rg == cg ? 1.0f : 0.0f);
          P[(size_t)rg * 1024 + cg] = f2bf(v);
        }
      }
    }
  } else {
#pragma unroll
    for (int i = 0; i < 4; ++i) {
      int rg0 = bm * 128 + wr * 64 + i * 16 + ((l >> 4) << 2);   // r = n*64+b
#pragma unroll
      for (int j = 0; j < NJ; ++j) {
        int cg = wc * 64 + j * 16 + (l & 15);                    // o
        float bv = bias[cg];
#pragma unroll
        for (int r = 0; r < 4; ++r) {
          int rg = rg0 + r;
          int drow = ((rg & 63) << 10) | (rg >> 6);              // b*1024 + n
          dout[(size_t)drow * 128 + cg] = acc[i][j][r] + bv;
        }
      }
    }
  }
}

// ---------------- launcher ----------------

extern "C" void kernel_launch(void* const* d_in, const int* in_sizes, int n_in,
                              void* d_out, int out_size, void* d_ws, size_t ws_size,
                              hipStream_t stream) {
  (void)in_sizes; (void)n_in; (void)out_size; (void)ws_size;
  const float* supports = (const float*)d_in[0];
  const float* inputs   = (const float*)d_in[1];
  const float* state    = (const float*)d_in[2];
  const float* weight   = (const float*)d_in[3];
  const float* bias     = (const float*)d_in[4];
  float* out = (float*)d_out;
  unsigned short* ws = (unsigned short*)d_ws;

  cvt_sup_kernel<<<2048, 256, 0, stream>>>(supports, ws);
  sup_t_kernel<<<dim3(16, 16, 2), 256, 0, stream>>>(ws);
  w2t_kernel<<<320, 256, 0, stream>>>(weight, ws);
  pack_kernel<<<dim3(64, 16, 2), 256, 0, stream>>>(inputs, state, ws);

  gemm_kernel<0, 2><<<dim3(8, 16, 2), 256, 0, stream>>>(ws, bias, out);  // P1,P3
  gemm8_kernel<<<512, 512, 131072, stream>>>(ws);                        // Y
  gemm_kernel<2, 4><<<512, 256, 0, stream>>>(ws, bias, out);             // out
}

// Round 4
// 127.858 us; speedup vs baseline: 1.1747x; 1.1747x over previous
//
#include <hip/hip_runtime.h>
#include <hip/hip_bf16.h>

// DiffusionGraphConv on MI355X (gfx950), bf16 MFMA pipeline, round 4.
//
// Pipeline (4 launches):
//   prep (fused): cvt_sup | sup_t(from f32) | w2t | pack   -- all read d_in only
//   psq  (128x32 2-phase GEMM, NJ=1): Pstack = [A1; 2A1^2-I; A2; 2A2^2-I]
//   big  (128x128 2-phase GEMM, NJ=4): Y = Pstack @ X0  (M=4096,N=8192,K=1024)
//   final(128x128 2-phase GEMM, NJ=4): out = [X0|Y] @ W2 + bias
//
// ws layout (bf16 elems):
//   PSTK 4M | SUPT 2M | X0T 8M | X0NF 8M | XNF 32M | W2T 80K

typedef short bf16x8  __attribute__((ext_vector_type(8)));
typedef short short4v __attribute__((ext_vector_type(4)));
typedef float f32x4   __attribute__((ext_vector_type(4)));

constexpr size_t MB1    = 1024ull * 1024ull;
constexpr size_t SZ_MAT = 8192ull * 1024ull;
constexpr size_t OFF_PSTK = 0;
constexpr size_t OFF_SUPT = 4 * MB1;
constexpr size_t OFF_X0T  = 6 * MB1;
constexpr size_t OFF_X0NF = OFF_X0T  + SZ_MAT;
constexpr size_t OFF_XNF  = OFF_X0NF + SZ_MAT;
constexpr size_t OFF_W2T  = OFF_XNF  + 4 * SZ_MAT;

__device__ __forceinline__ unsigned short f2bf(float x) {
  union { float f; unsigned int u; } v; v.f = x;
  unsigned int r = v.u + 0x7fffu + ((v.u >> 16) & 1u);   // RNE
  return (unsigned short)(r >> 16);
}

#define GLD16(gp, lp)                                                         \
  __builtin_amdgcn_global_load_lds(                                           \
      (const __attribute__((address_space(1))) unsigned int*)(gp),            \
      (__attribute__((address_space(3))) unsigned int*)(lp), 16, 0, 0)

// ---------------- fused prep kernel ----------------
// grid 4928 x 256thr:
//   [0,2048)    cvt_sup : f32 supports -> bf16 into PSTK rows 0,2
//   [2048,2560) sup_t   : f32 supports -> bf16 transposed into SUPT
//   [2560,2880) w2t     : weight repack [o][m*128+f]
//   [2880,4928) pack    : x0nf + x0t from inputs/state

__global__ __launch_bounds__(256)
void prep_kernel(const float* __restrict__ sup,
                 const float* __restrict__ weight,
                 const float* __restrict__ inputs,
                 const float* __restrict__ state,
                 unsigned short* __restrict__ ws) {
  __shared__ unsigned short tile[64][65];
  int bid = blockIdx.x;
  int tl  = threadIdx.x;

  if (bid < 2048) {                       // ---- cvt_sup
    size_t t = (size_t)bid * 256 + tl;    // < 524288 float4s
    const float4* src = (const float4*)sup;
    float4 v = src[t];
    size_t e = t * 4;
    size_t s = e >> 20;
    size_t r = e & (MB1 - 1);
    short4v o; o[0] = (short)f2bf(v.x); o[1] = (short)f2bf(v.y);
    o[2] = (short)f2bf(v.z); o[3] = (short)f2bf(v.w);
    *(short4v*)&ws[OFF_PSTK + 2 * s * MB1 + r] = o;
  } else if (bid < 2560) {                // ---- sup_t (from f32 source)
    int i = bid - 2048;
    int nt = i & 15, mt = (i >> 4) & 15, s = i >> 8;
    const float* A = sup + (size_t)s * MB1;
    unsigned short* AT = ws + OFF_SUPT + (size_t)s * MB1;
    int cl = tl & 63, rg = tl >> 6;
#pragma unroll 4
    for (int rr = 0; rr < 16; ++rr) {
      int rl = rr * 4 + rg;
      tile[rl][cl] = f2bf(A[(size_t)(nt * 64 + rl) * 1024 + mt * 64 + cl]);
    }
    __syncthreads();
#pragma unroll 4
    for (int rr = 0; rr < 16; ++rr) {
      int ml = rr * 4 + rg;
      AT[(size_t)(mt * 64 + ml) * 1024 + nt * 64 + cl] = tile[cl][ml];
    }
  } else if (bid < 2880) {                // ---- w2t
    int t = (bid - 2560) * 256 + tl;      // < 81920
    int o = t / 640, k = t % 640;
    int m = k >> 7, f = k & 127;
    ws[OFF_W2T + t] = f2bf(weight[(f * 5 + m) * 128 + o]);
  } else {                                // ---- pack
    int i = bid - 2880;                   // < 2048
    int b = i & 63, nt = (i >> 6) & 15, ft = i >> 10;
    const float* src = ft ? state : inputs;
    unsigned short* x0t  = ws + OFF_X0T;
    unsigned short* x0nf = ws + OFF_X0NF;
    int fl = tl & 63, nr = tl >> 6;
#pragma unroll 4
    for (int rr = 0; rr < 16; ++rr) {
      int n_loc = rr * 4 + nr;
      float v = src[(size_t)b * 65536 + (size_t)(nt * 64 + n_loc) * 64 + fl];
      unsigned short bv = f2bf(v);
      tile[n_loc][fl] = bv;
      x0nf[(size_t)(nt * 64 + n_loc) * 8192 + b * 128 + ft * 64 + fl] = bv;
    }
    __syncthreads();
#pragma unroll 4
    for (int rr = 0; rr < 16; ++rr) {
      int f_loc = rr * 4 + nr;
      x0t[(size_t)(b * 128 + ft * 64 + f_loc) * 1024 + nt * 64 + fl] =
          tile[fl][f_loc];
    }
  }
}

// ---------------- 128x(32*NJ) 2-phase GEMM core ----------------
// BK=64, 256 threads (4 waves 2x2), wave tile 64x(16*NJ),
// mfma_f32_16x16x32_bf16, global_load_lds w16, XOR-swizzled LDS.
//
// MODE 0 (NJ=1): psq   C[n][n'] = A_s @ A_s; epi 2*acc-I -> Pstack rows 1,3
// MODE 1 (NJ=4): big   Y = Pstack @ X0 (B^T=x0t), 2D XCD-rect grid
// MODE 2 (NJ=4): final out = [X0|Y] @ W2 + bias -> d_out f32

template <int MODE, int NJ>
__global__ __launch_bounds__(256)
void gemm_kernel(unsigned short* __restrict__ ws,
                 const float* __restrict__ bias,
                 float* __restrict__ dout) {
  __shared__ short At[128 * 64];
  __shared__ short Bt[32 * NJ * 64];

  const int tid = threadIdx.x;
  const int l   = tid & 63;
  const int w   = tid >> 6;
  const int wr  = w >> 1, wc = w & 1;

  int bm, bn, s = 0;
  const unsigned short* A = nullptr;
  const unsigned short* B;
  int KT;
  if constexpr (MODE == 0) {
    bm = blockIdx.x; bn = blockIdx.y; s = blockIdx.z;
    A = ws + OFF_PSTK + (size_t)(2 * s) * MB1;
    B = ws + OFF_SUPT + (size_t)s * MB1;
    KT = 16;
  } else if constexpr (MODE == 1) {
    // 2048 blocks; XCD rect: 8 XCDs as 2(bm) x 4(bn), each 16x16 tiles.
    int bid = blockIdx.x;
    int xcd = bid & 7, idx = bid >> 3;
    bm = ((xcd & 1) << 4) | (idx & 15);
    bn = ((xcd >> 1) << 4) | (idx >> 4);
    A = ws + OFF_PSTK;
    B = ws + OFF_X0T;
    KT = 16;
  } else {
    bm = blockIdx.x; bn = 0;
    B = ws + OFF_W2T;
    KT = 10;
  }

  const int subrow = l >> 3;
  const int koff   = (((l & 7) << 3) ^ (subrow << 3));

  f32x4 acc[4][NJ] = {};

  for (int kt = 0; kt < KT; ++kt) {
#pragma unroll
    for (int c = 0; c < 4; ++c) {
      int chunk = w * 4 + c;
      int rowl  = chunk * 8 + subrow;
      const unsigned short* gp;
      if constexpr (MODE == 2) {
        int rg = bm * 128 + rowl;
        const unsigned short* base =
            (kt < 2) ? (ws + OFF_X0NF)
                     : (ws + OFF_XNF + (size_t)((kt >> 1) - 1) * SZ_MAT);
        gp = base + (size_t)(rg >> 6) * 8192 + (size_t)(rg & 63) * 128 +
             (kt & 1) * 64 + koff;
      } else {
        gp = A + (size_t)(bm * 128 + rowl) * 1024 + kt * 64 + koff;
      }
      GLD16(gp, &At[chunk * 512]);
    }
#pragma unroll
    for (int c = 0; c < NJ; ++c) {
      int chunk = w * NJ + c;
      int rowl  = chunk * 8 + subrow;
      const unsigned short* gp;
      if constexpr (MODE == 2) {
        gp = B + (size_t)rowl * 640 + kt * 64 + koff;
      } else {
        gp = B + (size_t)(bn * (32 * NJ) + rowl) * 1024 + kt * 64 + koff;
      }
      GLD16(gp, &Bt[chunk * 512]);
    }
    __syncthreads();

#pragma unroll
    for (int kk = 0; kk < 2; ++kk) {
      bf16x8 af[4], bfv[NJ];
#pragma unroll
      for (int i = 0; i < 4; ++i) {
        int row = wr * 64 + i * 16 + (l & 15);
        int off = row * 64 + ((kk * 32 + ((l >> 4) << 3)) ^ ((row & 7) << 3));
        af[i] = *(const bf16x8*)&At[off];
      }
#pragma unroll
      for (int j = 0; j < NJ; ++j) {
        int row = wc * (16 * NJ) + j * 16 + (l & 15);
        int off = row * 64 + ((kk * 32 + ((l >> 4) << 3)) ^ ((row & 7) << 3));
        bfv[j] = *(const bf16x8*)&Bt[off];
      }
#pragma unroll
      for (int i = 0; i < 4; ++i)
#pragma unroll
        for (int j = 0; j < NJ; ++j)
          acc[i][j] = __builtin_amdgcn_mfma_f32_16x16x32_bf16(af[i], bfv[j],
                                                              acc[i][j], 0, 0, 0);
    }
    __syncthreads();
  }

  // ---------------- epilogues ----------------
  if constexpr (MODE == 0) {
    unsigned short* P = ws + OFF_PSTK + (size_t)(2 * s + 1) * MB1;
#pragma unroll
    for (int i = 0; i < 4; ++i) {
      int rg0 = bm * 128 + wr * 64 + i * 16 + ((l >> 4) << 2);
#pragma unroll
      for (int j = 0; j < NJ; ++j) {
        int cg = bn * (32 * NJ) + wc * (16 * NJ) + j * 16 + (l & 15);
#pragma unroll
        for (int r = 0; r < 4; ++r) {
          int rg = rg0 + r;
          float v = 2.0f * acc[i][j][r] - (rg == cg ? 1.0f : 0.0f);
          P[(size_t)rg * 1024 + cg] = f2bf(v);
        }
      }
    }
  } else if constexpr (MODE == 1) {
    unsigned short* Y = ws + OFF_XNF;           // [4096][8192] row-major
#pragma unroll
    for (int i = 0; i < 4; ++i) {
      int rg0 = bm * 128 + wr * 64 + i * 16 + ((l >> 4) << 2);
#pragma unroll
      for (int j = 0; j < NJ; ++j) {
        int cg = bn * 128 + wc * 64 + j * 16 + (l & 15);
#pragma unroll
        for (int r = 0; r < 4; ++r)
          Y[(size_t)(rg0 + r) * 8192 + cg] = f2bf(acc[i][j][r]);
      }
    }
  } else {
#pragma unroll
    for (int i = 0; i < 4; ++i) {
      int rg0 = bm * 128 + wr * 64 + i * 16 + ((l >> 4) << 2);   // r = n*64+b
#pragma unroll
      for (int j = 0; j < NJ; ++j) {
        int cg = wc * 64 + j * 16 + (l & 15);                    // o
        float bv = bias[cg];
#pragma unroll
        for (int r = 0; r < 4; ++r) {
          int rg = rg0 + r;
          int drow = ((rg & 63) << 10) | (rg >> 6);              // b*1024 + n
          dout[(size_t)drow * 128 + cg] = acc[i][j][r] + bv;
        }
      }
    }
  }
}

// ---------------- launcher ----------------

extern "C" void kernel_launch(void* const* d_in, const int* in_sizes, int n_in,
                              void* d_out, int out_size, void* d_ws, size_t ws_size,
                              hipStream_t stream) {
  (void)in_sizes; (void)n_in; (void)out_size; (void)ws_size;
  const float* supports = (const float*)d_in[0];
  const float* inputs   = (const float*)d_in[1];
  const float* state    = (const float*)d_in[2];
  const float* weight   = (const float*)d_in[3];
  const float* bias     = (const float*)d_in[4];
  float* out = (float*)d_out;
  unsigned short* ws = (unsigned short*)d_ws;

  prep_kernel<<<4928, 256, 0, stream>>>(supports, weight, inputs, state, ws);
  gemm_kernel<0, 1><<<dim3(8, 32, 2), 256, 0, stream>>>(ws, bias, out);  // P1,P3
  gemm_kernel<1, 4><<<2048, 256, 0, stream>>>(ws, bias, out);            // Y
  gemm_kernel<2, 4><<<512, 256, 0, stream>>>(ws, bias, out);             // out
}